// Round 7
// baseline (136.290 us; speedup 1.0000x reference)
//
#include <hip/hip_runtime.h>

#define TT 256      // T
#define DD 256      // D = H*DK
#define NH 4
#define DKK 64
#define NR 64
#define NB 4        // batch

#define FMA4(A, S, V) { A.x += (S)*(V).x; A.y += (S)*(V).y; A.z += (S)*(V).z; A.w += (S)*(V).w; }
#define DOT4(Q4, K4) ((Q4).x*(K4).x + (Q4).y*(K4).y + (Q4).z*(K4).z + (Q4).w*(K4).w)

// ---------------- Kernel 1: fused QKV projection ----------------
// (measured healthy; untouched)
__global__ __launch_bounds__(256) void k_qkv(
    const float* __restrict__ x,
    const float* __restrict__ Wq, const float* __restrict__ bq,
    const float* __restrict__ Wk, const float* __restrict__ bk,
    const float* __restrict__ Wv, const float* __restrict__ bv,
    float* __restrict__ Q, float* __restrict__ K, float* __restrict__ V)
{
    const int z = blockIdx.z;
    const float* __restrict__ W    = (z == 0) ? Wq : (z == 1) ? Wk : Wv;
    const float* __restrict__ bias = (z == 0) ? bq : (z == 1) ? bk : bv;
    float* __restrict__ out        = (z == 0) ? Q  : (z == 1) ? K  : V;
    const int r0 = blockIdx.x * 16, c0 = blockIdx.y * 64;
    __shared__ float xl[16][68];
    __shared__ float wl[64][68];
    const int t = threadIdx.x;
    const int cg = t & 15, rg = t >> 4;
    float acc[4] = {};
    for (int kt = 0; kt < 4; ++kt) {
        const int kb = kt * 64;
        {
            const int r = t >> 4, q4 = t & 15;
            *(float4*)&xl[r][q4 * 4] = *(const float4*)&x[(r0 + r) * DD + kb + q4 * 4];
        }
        #pragma unroll
        for (int u = 0; u < 4; ++u) {
            const int idx = u * 256 + t;
            const int r = idx >> 4, q4 = idx & 15;
            *(float4*)&wl[r][q4 * 4] = *(const float4*)&W[(c0 + r) * DD + kb + q4 * 4];
        }
        __syncthreads();
        #pragma unroll 4
        for (int d4 = 0; d4 < 64; d4 += 4) {
            const float4 xv = *(const float4*)&xl[rg][d4];
            #pragma unroll
            for (int c = 0; c < 4; ++c) {
                const float4 wv = *(const float4*)&wl[cg + 16 * c][d4];
                acc[c] += DOT4(xv, wv);
            }
        }
        __syncthreads();
    }
    const int r = r0 + rg;
    #pragma unroll
    for (int c = 0; c < 4; ++c) {
        const int cc = c0 + cg + 16 * c;
        out[r * DD + cc] = acc[c] + bias[cc];
    }
}

// ---------------- Kernel 2: relational attention v3 ----------------
// grid (16 i-tiles, H, B) = 256 blocks, block 256, LDS ~45 KB, no big reg arrays.
// All global accesses coalesced (float4, consecutive lanes). K/rel_k/V time-share
// one 16-KB chunk buffer with XOR chunk swizzle (row-per-lane reads conflict-free).
// Verified algebra: score = q.k + qr[i,sm];  out = P.V + sum_r w[i,r] rel_v_r.
__global__ __launch_bounds__(256) void k_attn(
    const float* __restrict__ Q, const float* __restrict__ K, const float* __restrict__ V,
    const int* __restrict__ SM,
    const float* __restrict__ relk, const float* __restrict__ relv,
    float* __restrict__ AGG)
{
    const int it = blockIdx.x, h = blockIdx.y, b = blockIdx.z;
    const int i0 = it * 16;
    __shared__ float kch[64][64];            // 16 KB: K-chunk / rel_k / V-chunk
    __shared__ float ql[16][64];             //  4 KB (reads are wave-uniform)
    __shared__ float sl[16][260];            // 16.6 KB scores -> probs
    __shared__ float qrl[16][64];            //  4 KB
    __shared__ float wlh[16][64];            //  4 KB histogram
    __shared__ unsigned char smlp[16][256];  //  4 KB packed ids

    const int t = threadIdx.x;
    // XOR-swizzled f4-chunk address: logical chunk k of row r
    #define KCHP(r, k) (&kch[(r)][((((k) + ((r) >> 3)) & 15)) * 4])

    // ---- phase 1: stage Q + packed SM, zero histogram ----
    {
        const int r = t >> 4, q4 = t & 15;
        *(float4*)&ql[r][q4 * 4] = *(const float4*)&Q[(b * TT + i0 + r) * DD + h * DKK + q4 * 4];
    }
    #pragma unroll
    for (int u = 0; u < 4; ++u) {
        const int idx = u * 256 + t;
        const int i = idx >> 6, j4 = idx & 63;
        const int4 s4 = *(const int4*)&SM[(b * TT + i0 + i) * TT + j4 * 4];
        const unsigned int pk = (unsigned int)(s4.x & 255) | ((unsigned int)(s4.y & 255) << 8)
                              | ((unsigned int)(s4.z & 255) << 16) | ((unsigned int)(s4.w & 255) << 24);
        *(unsigned int*)&smlp[i][j4 * 4] = pk;
    }
    {
        float* wf = &wlh[0][0];
        wf[t] = 0.f; wf[t + 256] = 0.f; wf[t + 512] = 0.f; wf[t + 768] = 0.f;
    }
    __syncthreads();

    // ---- phase 2: raw scores, K staged in 4 chunks of 64 rows ----
    for (int c = 0; c < 4; ++c) {
        #pragma unroll
        for (int u = 0; u < 4; ++u) {
            const int idx = u * 256 + t;
            const int r = idx >> 4, q4 = idx & 15;
            *(float4*)KCHP(r, q4) = *(const float4*)&K[(b * TT + c * 64 + r) * DD + h * DKK + q4 * 4];
        }
        __syncthreads();
        {
            const int jl = t & 63, ig = t >> 6;
            float a0 = 0.f, a1 = 0.f, a2 = 0.f, a3 = 0.f;
            #pragma unroll 4
            for (int d4 = 0; d4 < 64; d4 += 4) {
                const float4 k4 = *(const float4*)KCHP(jl, d4 >> 2);
                const float4 q0 = *(const float4*)&ql[ig * 4 + 0][d4];
                const float4 q1 = *(const float4*)&ql[ig * 4 + 1][d4];
                const float4 q2 = *(const float4*)&ql[ig * 4 + 2][d4];
                const float4 q3 = *(const float4*)&ql[ig * 4 + 3][d4];
                a0 += DOT4(q0, k4); a1 += DOT4(q1, k4);
                a2 += DOT4(q2, k4); a3 += DOT4(q3, k4);
            }
            sl[ig * 4 + 0][c * 64 + jl] = a0;
            sl[ig * 4 + 1][c * 64 + jl] = a1;
            sl[ig * 4 + 2][c * 64 + jl] = a2;
            sl[ig * 4 + 3][c * 64 + jl] = a3;
        }
        __syncthreads();
    }

    // ---- phase 3: qr[i][r] = q_i . rel_k_r (rel_k staged through kch) ----
    #pragma unroll
    for (int u = 0; u < 4; ++u) {
        const int idx = u * 256 + t;
        const int r = idx >> 4, q4 = idx & 15;
        *(float4*)KCHP(r, q4) = *(const float4*)&relk[r * DD + h * DKK + q4 * 4];
    }
    __syncthreads();
    {
        const int r = t & 63, ig = t >> 6;
        float a0 = 0.f, a1 = 0.f, a2 = 0.f, a3 = 0.f;
        #pragma unroll 4
        for (int d4 = 0; d4 < 64; d4 += 4) {
            const float4 rk4 = *(const float4*)KCHP(r, d4 >> 2);
            const float4 q0 = *(const float4*)&ql[ig * 4 + 0][d4];
            const float4 q1 = *(const float4*)&ql[ig * 4 + 1][d4];
            const float4 q2 = *(const float4*)&ql[ig * 4 + 2][d4];
            const float4 q3 = *(const float4*)&ql[ig * 4 + 3][d4];
            a0 += DOT4(q0, rk4); a1 += DOT4(q1, rk4);
            a2 += DOT4(q2, rk4); a3 += DOT4(q3, rk4);
        }
        qrl[ig * 4 + 0][r] = a0;
        qrl[ig * 4 + 1][r] = a1;
        qrl[ig * 4 + 2][r] = a2;
        qrl[ig * 4 + 3][r] = a3;
    }
    __syncthreads();

    // ---- phase 4: softmax (16 lanes/row) + histogram; fold qr-add and scale ----
    {
        const int row = t >> 4, g = t & 15;
        float vals[16];
        float m = -1e30f;
        #pragma unroll
        for (int jj = 0; jj < 16; ++jj) {
            const int j = g + jj * 16;
            vals[jj] = (sl[row][j] + qrl[row][smlp[row][j]]) * 0.125f;   // 1/sqrt(64)
            m = fmaxf(m, vals[jj]);
        }
        #pragma unroll
        for (int off = 8; off; off >>= 1) m = fmaxf(m, __shfl_xor(m, off, 16));
        float s = 0.f;
        #pragma unroll
        for (int jj = 0; jj < 16; ++jj) { vals[jj] = __expf(vals[jj] - m); s += vals[jj]; }
        #pragma unroll
        for (int off = 8; off; off >>= 1) s += __shfl_xor(s, off, 16);
        const float inv = 1.0f / s;
        #pragma unroll
        for (int jj = 0; jj < 16; ++jj) {
            const int j = g + jj * 16;
            const float p = vals[jj] * inv;
            sl[row][j] = p;
            atomicAdd(&wlh[row][smlp[row][j]], p);
        }
    }
    __syncthreads();

    // ---- phase 5: PV, V staged in 4 chunks; lane owns (i = 4*wave+ig, d = 4*dg) ----
    const int w5 = t >> 6, l5 = t & 63;
    const int dg = l5 & 15, ig5 = l5 >> 4;
    const int i5 = w5 * 4 + ig5;
    float4 acc = {0.f, 0.f, 0.f, 0.f};
    for (int c = 0; c < 4; ++c) {
        #pragma unroll
        for (int u = 0; u < 4; ++u) {
            const int idx = u * 256 + t;
            const int r = idx >> 4, q4 = idx & 15;
            *(float4*)KCHP(r, q4) = *(const float4*)&V[(b * TT + c * 64 + r) * DD + h * DKK + q4 * 4];
        }
        __syncthreads();
        #pragma unroll 4
        for (int jl = 0; jl < 64; jl += 4) {
            const float4 p4 = *(const float4*)&sl[i5][c * 64 + jl];
            FMA4(acc, p4.x, *(const float4*)KCHP(jl + 0, dg));
            FMA4(acc, p4.y, *(const float4*)KCHP(jl + 1, dg));
            FMA4(acc, p4.z, *(const float4*)KCHP(jl + 2, dg));
            FMA4(acc, p4.w, *(const float4*)KCHP(jl + 3, dg));
        }
        __syncthreads();
    }

    // ---- phase 6: + histogram x rel_v (coalesced), write AGG ----
    {
        #pragma unroll 4
        for (int r = 0; r < 64; ++r) {
            const float wv = wlh[i5][r];
            const float4 rv = *(const float4*)&relv[r * DD + h * DKK + dg * 4];
            FMA4(acc, wv, rv);
        }
        *(float4*)&AGG[(b * TT + i0 + i5) * DD + h * DKK + dg * 4] = acc;
    }
    #undef KCHP
}

// ---------------- Kernel 3: out projection + bias + residual ----------------
__global__ __launch_bounds__(256) void k_oproj(
    const float* __restrict__ AGG, const float* __restrict__ Wo,
    const float* __restrict__ bo, const float* __restrict__ x,
    float* __restrict__ OPRE)
{
    const int r0 = blockIdx.x * 16, c0 = blockIdx.y * 64;
    __shared__ float al[16][68];
    __shared__ float wl[64][68];
    const int t = threadIdx.x;
    const int cg = t & 15, rg = t >> 4;
    float acc[4] = {};
    for (int kt = 0; kt < 4; ++kt) {
        const int kb = kt * 64;
        {
            const int r = t >> 4, q4 = t & 15;
            *(float4*)&al[r][q4 * 4] = *(const float4*)&AGG[(r0 + r) * DD + kb + q4 * 4];
        }
        #pragma unroll
        for (int u = 0; u < 4; ++u) {
            const int idx = u * 256 + t;
            const int r = idx >> 4, q4 = idx & 15;
            *(float4*)&wl[r][q4 * 4] = *(const float4*)&Wo[(c0 + r) * DD + kb + q4 * 4];
        }
        __syncthreads();
        #pragma unroll 4
        for (int d4 = 0; d4 < 64; d4 += 4) {
            const float4 av = *(const float4*)&al[rg][d4];
            #pragma unroll
            for (int c = 0; c < 4; ++c) {
                const float4 wv = *(const float4*)&wl[cg + 16 * c][d4];
                acc[c] += DOT4(av, wv);
            }
        }
        __syncthreads();
    }
    const int r = r0 + rg;
    #pragma unroll
    for (int c = 0; c < 4; ++c) {
        const int cc = c0 + cg + 16 * c;
        OPRE[r * DD + cc] = acc[c] + bo[cc] + x[r * DD + cc];
    }
}

// ---------------- Kernel 4: LayerNorm + ReLU (one wave per row) ----------------
__global__ __launch_bounds__(256) void k_ln(
    const float* __restrict__ OPRE, const float* __restrict__ gamma,
    const float* __restrict__ beta, float* __restrict__ out)
{
    const int row = blockIdx.x * 4 + (threadIdx.x >> 6);
    const int lane = threadIdx.x & 63;
    const float4 v = *(const float4*)&OPRE[row * DD + lane * 4];
    float s  = v.x + v.y + v.z + v.w;
    float sq = v.x * v.x + v.y * v.y + v.z * v.z + v.w * v.w;
    #pragma unroll
    for (int off = 32; off; off >>= 1) {
        s  += __shfl_xor(s, off, 64);
        sq += __shfl_xor(sq, off, 64);
    }
    const float mu   = s * (1.0f / DD);
    const float rstd = rsqrtf(sq * (1.0f / DD) - mu * mu + 1e-5f);
    const float4 g  = *(const float4*)&gamma[lane * 4];
    const float4 bt = *(const float4*)&beta[lane * 4];
    float4 o;
    o.x = fmaxf((v.x - mu) * rstd * g.x + bt.x, 0.f);
    o.y = fmaxf((v.y - mu) * rstd * g.y + bt.y, 0.f);
    o.z = fmaxf((v.z - mu) * rstd * g.z + bt.z, 0.f);
    o.w = fmaxf((v.w - mu) * rstd * g.w + bt.w, 0.f);
    *(float4*)&out[row * DD + lane * 4] = o;
}

extern "C" void kernel_launch(void* const* d_in, const int* in_sizes, int n_in,
                              void* d_out, int out_size, void* d_ws, size_t ws_size,
                              hipStream_t stream)
{
    (void)in_sizes; (void)n_in; (void)out_size; (void)ws_size;
    const float* x     = (const float*)d_in[0];
    const int*   SM    = (const int*)d_in[1];
    const float* Wq    = (const float*)d_in[2];
    const float* bq    = (const float*)d_in[3];
    const float* Wk    = (const float*)d_in[4];
    const float* bk    = (const float*)d_in[5];
    const float* Wv    = (const float*)d_in[6];
    const float* bv    = (const float*)d_in[7];
    const float* relk  = (const float*)d_in[8];
    const float* relv  = (const float*)d_in[9];
    const float* Wo    = (const float*)d_in[10];
    const float* bo    = (const float*)d_in[11];
    const float* gamma = (const float*)d_in[12];
    const float* beta  = (const float*)d_in[13];
    float* out = (float*)d_out;
    float* ws  = (float*)d_ws;

    const int NTD = NB * TT * DD;   // 262144 floats
    float* Q  = ws;
    float* K  = ws + NTD;
    float* V  = ws + 2 * NTD;
    float* AG = ws + 3 * NTD;
    float* OP = ws + 4 * NTD;

    k_qkv  <<<dim3(64, 4, 3), 256, 0, stream>>>(x, Wq, bq, Wk, bk, Wv, bv, Q, K, V);
    k_attn <<<dim3(16, NH, NB), 256, 0, stream>>>(Q, K, V, SM, relk, relv, AG);
    k_oproj<<<dim3(64, 4), 256, 0, stream>>>(AG, Wo, bo, x, OP);
    k_ln   <<<256, 256, 0, stream>>>(OP, gamma, beta, out);
}